// Round 7
// baseline (881.605 us; speedup 1.0000x reference)
//
#include <hip/hip_runtime.h>

#define T    256
#define EPB  2048               // edges per block
#define NPAD 102400             // padded N for accumulator arrays

typedef int   i4 __attribute__((ext_vector_type(4)));
typedef float f4 __attribute__((ext_vector_type(4)));

__device__ __forceinline__ void gadd(float* a, float v) {
    unsafeAtomicAdd(a, v);      // native global_atomic_add_f32 (no CAS loop)
}

// ---------- degree: deg[col] += w ----------
__global__ __launch_bounds__(T) void k_deg(const int* __restrict__ col,
                                           const float* __restrict__ w,
                                           float* __restrict__ deg, int E) {
    int t = threadIdx.x;
    long base = (long)blockIdx.x * EPB;
    if (base + EPB <= E) {
#pragma unroll
        for (int k = 0; k < 2; ++k) {
            long idx = base + (t + k * T) * 4;
            i4 c  = __builtin_nontemporal_load((const i4*)(col + idx));
            f4 wv = __builtin_nontemporal_load((const f4*)(w + idx));
            gadd(&deg[c.x], wv.x);
            gadd(&deg[c.y], wv.y);
            gadd(&deg[c.z], wv.z);
            gadd(&deg[c.w], wv.w);
        }
    } else {
        for (int k = 0; k < 8; ++k) {
            long e = base + t + k * T;
            if (e < E) gadd(&deg[col[e]], w[e]);
        }
    }
}

// ---------- message pass: dst[col] += w * src[row] ----------
__global__ __launch_bounds__(T) void k_mp(const int* __restrict__ row,
                                          const int* __restrict__ col,
                                          const float* __restrict__ w,
                                          const float* __restrict__ src,
                                          float* __restrict__ dst, int E) {
    int t = threadIdx.x;
    long base = (long)blockIdx.x * EPB;
    if (base + EPB <= E) {
#pragma unroll
        for (int k = 0; k < 2; ++k) {
            long idx = base + (t + k * T) * 4;
            i4 c  = __builtin_nontemporal_load((const i4*)(col + idx));
            i4 r  = __builtin_nontemporal_load((const i4*)(row + idx));
            f4 wv = __builtin_nontemporal_load((const f4*)(w + idx));
            gadd(&dst[c.x], wv.x * src[r.x]);
            gadd(&dst[c.y], wv.y * src[r.y]);
            gadd(&dst[c.z], wv.z * src[r.z]);
            gadd(&dst[c.w], wv.w * src[r.w]);
        }
    } else {
        for (int k = 0; k < 8; ++k) {
            long e = base + t + k * T;
            if (e < E) gadd(&dst[col[e]], w[e] * src[row[e]]);
        }
    }
}

// ---------- node-wise kernels ----------
__global__ void k_dinv(const float* __restrict__ deg, const float* __restrict__ x,
                       float* __restrict__ dinv, float* __restrict__ p, int N) {
    int i = blockIdx.x * blockDim.x + threadIdx.x;
    if (i < N) {
        float d  = deg[i] + 1.0f;               // +1 = self-loop
        float di = rsqrtf(d);
        dinv[i] = di;
        p[i] = di * x[i];
    }
}

__global__ void k_mlp(const float* __restrict__ s1, const float* __restrict__ dinv,
                      const float* __restrict__ p,
                      const float* __restrict__ W1, const float* __restrict__ b1,
                      const float* __restrict__ W2,
                      float* __restrict__ q, int N) {
    int i = blockIdx.x * blockDim.x + threadIdx.x;
    if (i < N) {
        float di = dinv[i];
        float s  = di * s1[i] + di * p[i];
        float acc = 0.0f;
#pragma unroll
        for (int k = 0; k < 16; ++k) {
            float h = fmaxf(s * W1[k] + b1[k], 0.0f);
            acc += h * W2[k];
        }
        q[i] = di * acc;
    }
}

__global__ void k_out(const float* __restrict__ s2, const float* __restrict__ dinv,
                      const float* __restrict__ q, const float* __restrict__ b2,
                      float* __restrict__ out, int N) {
    int i = blockIdx.x * blockDim.x + threadIdx.x;
    if (i < N) {
        float di = dinv[i];
        out[i] = di * s2[i] + di * q[i] + b2[0];
    }
}

extern "C" void kernel_launch(void* const* d_in, const int* in_sizes, int n_in,
                              void* d_out, int out_size, void* d_ws, size_t ws_size,
                              hipStream_t stream) {
    const float* x  = (const float*)d_in[0];
    const int*   ei = (const int*)  d_in[1];
    const float* ew = (const float*)d_in[2];
    const float* W1 = (const float*)d_in[3];
    const float* b1 = (const float*)d_in[4];
    const float* W2 = (const float*)d_in[5];
    const float* b2 = (const float*)d_in[6];

    const int N = in_sizes[0];       // x is [N,1]
    const int E = in_sizes[2];       // edge_attr is [E]
    const int* row = ei;             // edge_index[0] = source
    const int* col = ei + E;         // edge_index[1] = target

    // workspace: 3 accumulators (zeroed each call) + dinv, p, q
    char* wsp = (char*)d_ws;
    auto take = [&](size_t bytes) {
        char* r = wsp; wsp += (bytes + 255) & ~(size_t)255; return (void*)r;
    };
    float* zbase = (float*)take((size_t)3 * NPAD * 4);   // deg | s1 | s2, contiguous
    float* deg   = zbase;
    float* s1    = zbase + NPAD;
    float* s2    = zbase + 2 * NPAD;
    float* dinv  = (float*)take((size_t)N * 4);
    float* p     = (float*)take((size_t)N * 4);
    float* q     = (float*)take((size_t)N * 4);

    float* out = (float*)d_out;

    const int ebk = (E + EPB - 1) / EPB;         // 2442
    const int nbk = (N + T - 1) / T;             // 391

    (void)hipMemsetAsync(zbase, 0, (size_t)3 * NPAD * 4, stream);

    // degree
    k_deg <<<ebk, T, 0, stream>>>(col, ew, deg, E);
    k_dinv<<<nbk, T, 0, stream>>>(deg, x, dinv, p, N);

    // layer 1
    k_mp  <<<ebk, T, 0, stream>>>(row, col, ew, p, s1, E);
    k_mlp <<<nbk, T, 0, stream>>>(s1, dinv, p, W1, b1, W2, q, N);

    // layer 2
    k_mp  <<<ebk, T, 0, stream>>>(row, col, ew, q, s2, E);
    k_out <<<nbk, T, 0, stream>>>(s2, dinv, q, b2, out, N);
}

// Round 8
// 324.267 us; speedup vs baseline: 2.7188x; 2.7188x over previous
//
#include <hip/hip_runtime.h>

#define T     256
#define BS    4096              // nodes per bucket
#define NB    25                // buckets (N=100000 fixed)
#define NT2   (NB * NB)         // 625 tiles
#define EPB   8192              // edges per count/scatter block
#define TCAP  9856              // records per tile: mean 8389 + 16 sigma, even

typedef int   i4 __attribute__((ext_vector_type(4)));
typedef int   i2 __attribute__((ext_vector_type(2)));
typedef float f4 __attribute__((ext_vector_type(4)));

// ---------- K1 count: per-block 625-tile histogram ----------
__global__ __launch_bounds__(T) void k_count(const int* __restrict__ row,
                                             const int* __restrict__ col,
                                             int* __restrict__ cntT,
                                             int E, int ebp) {
    __shared__ int hist[NT2];
    int t = threadIdx.x, g = blockIdx.x;
    for (int j = t; j < NT2; j += T) hist[j] = 0;
    __syncthreads();
    long base = (long)g * EPB;
    if (base + EPB <= E) {
#pragma unroll
        for (int k = 0; k < 8; ++k) {
            long idx = base + (t + k * T) * 4;
            i4 c = *(const i4*)(col + idx);
            i4 r = *(const i4*)(row + idx);
            atomicAdd(&hist[(c.x >> 12) * NB + (r.x >> 12)], 1);
            atomicAdd(&hist[(c.y >> 12) * NB + (r.y >> 12)], 1);
            atomicAdd(&hist[(c.z >> 12) * NB + (r.z >> 12)], 1);
            atomicAdd(&hist[(c.w >> 12) * NB + (r.w >> 12)], 1);
        }
    } else {
        for (int k = 0; k < 32; ++k) {
            long e = base + t + (long)k * T;
            if (e < E) atomicAdd(&hist[(col[e] >> 12) * NB + (row[e] >> 12)], 1);
        }
    }
    __syncthreads();
    for (int j = t; j < NT2; j += T) cntT[j * ebp + g] = hist[j];
}

// ---------- K2 scan: one block per tile, exclusive scan over eb blocks ----------
__global__ __launch_bounds__(T) void k_scan(const int* __restrict__ cntT,
                                            int* __restrict__ ofsT,
                                            int* __restrict__ tot, int eb, int ebp) {
    __shared__ int wsum[4];
    __shared__ int carry;
    int b = blockIdx.x, t = threadIdx.x, lane = t & 63, wid = t >> 6;
    if (t == 0) carry = 0;
    __syncthreads();
    int rounds = (eb + T - 1) / T;
    for (int jr = 0; jr < rounds; ++jr) {
        int idx = jr * T + t;
        int v = (idx < eb) ? cntT[b * ebp + idx] : 0;
        int inc = v;
#pragma unroll
        for (int d = 1; d < 64; d <<= 1) {
            int o = __shfl_up(inc, d, 64);
            if (lane >= d) inc += o;
        }
        if (lane == 63) wsum[wid] = inc;
        __syncthreads();
        int add = carry;
        for (int w = 0; w < wid; ++w) add += wsum[w];
        if (idx < eb) ofsT[b * ebp + idx] = inc - v + add;
        __syncthreads();
        if (t == 0) carry += wsum[0] + wsum[1] + wsum[2] + wsum[3];
        __syncthreads();
    }
    if (t == 0) tot[b] = carry;
}

// ---------- K3 scatter: LDS 625-way bucket sort, packed per-tile output ----------
// record.x = (row_local << 12) | col_local, record.y = bits(w)
__global__ __launch_bounds__(T) void k_scatter(
        const int* __restrict__ row, const int* __restrict__ col,
        const float* __restrict__ w, const int* __restrict__ ofsT,
        i2* __restrict__ rec, int E, int ebp) {
    __shared__ i2  buf[EPB];                   // 64 KB
    __shared__ int rnk[NT2];
    __shared__ int lofs[NT2 + 1];
    __shared__ int rbase[NT2];
    __shared__ int wsum[4];
    __shared__ int carry;
    int t = threadIdx.x, g = blockIdx.x, lane = t & 63, wid = t >> 6;
    for (int j = t; j < NT2; j += T) rnk[j] = 0;
    if (t == 0) carry = 0;
    __syncthreads();
    long base = (long)g * EPB;
    bool full = (base + EPB <= E);
    i4 cc[8], rr[8];
    if (full) {
#pragma unroll
        for (int k = 0; k < 8; ++k) {
            long idx = base + (t + k * T) * 4;
            cc[k] = *(const i4*)(col + idx);
            rr[k] = *(const i4*)(row + idx);
            atomicAdd(&rnk[(cc[k].x >> 12) * NB + (rr[k].x >> 12)], 1);
            atomicAdd(&rnk[(cc[k].y >> 12) * NB + (rr[k].y >> 12)], 1);
            atomicAdd(&rnk[(cc[k].z >> 12) * NB + (rr[k].z >> 12)], 1);
            atomicAdd(&rnk[(cc[k].w >> 12) * NB + (rr[k].w >> 12)], 1);
        }
    } else {
        for (int k = 0; k < 32; ++k) {
            long e = base + t + (long)k * T;
            if (e < E) atomicAdd(&rnk[(col[e] >> 12) * NB + (row[e] >> 12)], 1);
        }
    }
    __syncthreads();
    // block-wide exclusive scan of rnk[0..625) -> lofs
    int rounds = (NT2 + T - 1) / T;            // 3
    for (int jr = 0; jr < rounds; ++jr) {
        int idx = jr * T + t;
        int v = (idx < NT2) ? rnk[idx] : 0;
        int inc = v;
#pragma unroll
        for (int d = 1; d < 64; d <<= 1) {
            int o = __shfl_up(inc, d, 64);
            if (lane >= d) inc += o;
        }
        if (lane == 63) wsum[wid] = inc;
        __syncthreads();
        int add = carry;
        for (int wv = 0; wv < wid; ++wv) add += wsum[wv];
        if (idx < NT2) lofs[idx + 1] = inc + add;
        __syncthreads();
        if (t == 0) carry += wsum[0] + wsum[1] + wsum[2] + wsum[3];
        __syncthreads();
    }
    if (t == 0) lofs[0] = 0;
    for (int j = t; j < NT2; j += T) {
        rbase[j] = j * TCAP + ofsT[j * ebp + g];
        rnk[j] = 0;                            // reuse as placement cursor
    }
    __syncthreads();
    auto place = [&](int c, int r, float wv) {
        int b = (c >> 12) * NB + (r >> 12);
        int pos = lofs[b] + atomicAdd(&rnk[b], 1);
        i2 v;
        v.x = ((r & (BS - 1)) << 12) | (c & (BS - 1));
        v.y = __float_as_int(wv);
        buf[pos] = v;
    };
    if (full) {
#pragma unroll
        for (int k = 0; k < 8; ++k) {
            long idx = base + (t + k * T) * 4;
            f4 wv = *(const f4*)(w + idx);
            place(cc[k].x, rr[k].x, wv.x);
            place(cc[k].y, rr[k].y, wv.y);
            place(cc[k].z, rr[k].z, wv.z);
            place(cc[k].w, rr[k].w, wv.w);
        }
    } else {
        for (int k = 0; k < 32; ++k) {
            long e = base + t + (long)k * T;
            if (e < E) place(col[e], row[e], w[e]);
        }
    }
    __syncthreads();
    // coalesced copy-out; tile recovered monotonically from lofs
    int total = lofs[NT2];
    int b = 0;
    for (int j = t; j < total; j += T) {
        while (j >= lofs[b + 1]) ++b;
        rec[rbase[b] + (j - lofs[b])] = buf[j];
    }
}

// ---------- K acc2: one block per tile; src slice + accumulator both in LDS ----------
template <bool HAS_SRC>
__global__ __launch_bounds__(T) void k_acc2(
        const i2* __restrict__ rec, const int* __restrict__ tot,
        const float* __restrict__ src, float* __restrict__ part, int N) {
    __shared__ float accl[BS];                 // 16 KB
    __shared__ float srcl[HAS_SRC ? BS : 64];  // +16 KB when gathering
    int t = threadIdx.x, tid = blockIdx.x;
    int rb = tid % NB;
    f4* acc4 = (f4*)accl;
    for (int j = t; j < BS / 4; j += T) acc4[j] = (f4){0.f, 0.f, 0.f, 0.f};
    if (HAS_SRC) {
        int s0 = rb * BS;
        for (int j = t; j < BS; j += T)
            srcl[j] = (s0 + j < N) ? src[s0 + j] : 0.0f;
    }
    __syncthreads();
    int lo = tid * TCAP;
    int hi = lo + tot[tid];
    const i4* rec4 = (const i4*)rec;
    int i = lo + t * 8;
    for (; i + 7 < hi; i += T * 8) {
        i4 q0 = rec4[(i >> 1) + 0];
        i4 q1 = rec4[(i >> 1) + 1];
        i4 q2 = rec4[(i >> 1) + 2];
        i4 q3 = rec4[(i >> 1) + 3];
        float v0 = __int_as_float(q0.y), v1 = __int_as_float(q0.w);
        float v2 = __int_as_float(q1.y), v3 = __int_as_float(q1.w);
        float v4 = __int_as_float(q2.y), v5 = __int_as_float(q2.w);
        float v6 = __int_as_float(q3.y), v7 = __int_as_float(q3.w);
        if (HAS_SRC) {
            v0 *= srcl[(q0.x >> 12) & (BS - 1)]; v1 *= srcl[(q0.z >> 12) & (BS - 1)];
            v2 *= srcl[(q1.x >> 12) & (BS - 1)]; v3 *= srcl[(q1.z >> 12) & (BS - 1)];
            v4 *= srcl[(q2.x >> 12) & (BS - 1)]; v5 *= srcl[(q2.z >> 12) & (BS - 1)];
            v6 *= srcl[(q3.x >> 12) & (BS - 1)]; v7 *= srcl[(q3.z >> 12) & (BS - 1)];
        }
        atomicAdd(&accl[q0.x & (BS - 1)], v0);
        atomicAdd(&accl[q0.z & (BS - 1)], v1);
        atomicAdd(&accl[q1.x & (BS - 1)], v2);
        atomicAdd(&accl[q1.z & (BS - 1)], v3);
        atomicAdd(&accl[q2.x & (BS - 1)], v4);
        atomicAdd(&accl[q2.z & (BS - 1)], v5);
        atomicAdd(&accl[q3.x & (BS - 1)], v6);
        atomicAdd(&accl[q3.z & (BS - 1)], v7);
    }
    for (; i < hi; ++i) {                      // tail: at most one thread, <=7 records
        i2 r = rec[i];
        float v = __int_as_float(r.y);
        if (HAS_SRC) v *= srcl[(r.x >> 12) & (BS - 1)];
        atomicAdd(&accl[r.x & (BS - 1)], v);
    }
    __syncthreads();
    f4* dst4 = (f4*)(part + (size_t)tid * BS);
    for (int j = t; j < BS / 4; j += T) dst4[j] = acc4[j];
}

// ---------- reduce + pointwise ----------
__device__ __forceinline__ float reduceT(const float* __restrict__ part, int n) {
    int cb = n >> 12, o = n & (BS - 1);
    const float* pp = part + (size_t)cb * NB * BS + o;
    float s = 0.0f;
#pragma unroll
    for (int rb = 0; rb < NB; ++rb) s += pp[(size_t)rb * BS];
    return s;
}

__global__ void k_dinv(const float* __restrict__ part, const float* __restrict__ x,
                       float* __restrict__ dinv, float* __restrict__ p, int N) {
    int i = blockIdx.x * blockDim.x + threadIdx.x;
    if (i < N) {
        float d  = reduceT(part, i) + 1.0f;     // +1 = self-loop
        float di = rsqrtf(d);
        dinv[i] = di;
        p[i] = di * x[i];
    }
}

__global__ void k_mlp(const float* __restrict__ part, const float* __restrict__ dinv,
                      const float* __restrict__ p,
                      const float* __restrict__ W1, const float* __restrict__ b1,
                      const float* __restrict__ W2,
                      float* __restrict__ q, int N) {
    int i = blockIdx.x * blockDim.x + threadIdx.x;
    if (i < N) {
        float di = dinv[i];
        float s  = di * reduceT(part, i) + di * p[i];
        float acc = 0.0f;
#pragma unroll
        for (int k = 0; k < 16; ++k) {
            float h = fmaxf(s * W1[k] + b1[k], 0.0f);
            acc += h * W2[k];
        }
        q[i] = di * acc;
    }
}

__global__ void k_out(const float* __restrict__ part, const float* __restrict__ dinv,
                      const float* __restrict__ q, const float* __restrict__ b2,
                      float* __restrict__ out, int N) {
    int i = blockIdx.x * blockDim.x + threadIdx.x;
    if (i < N) {
        float di = dinv[i];
        out[i] = di * reduceT(part, i) + di * q[i] + b2[0];
    }
}

extern "C" void kernel_launch(void* const* d_in, const int* in_sizes, int n_in,
                              void* d_out, int out_size, void* d_ws, size_t ws_size,
                              hipStream_t stream) {
    const float* x  = (const float*)d_in[0];
    const int*   ei = (const int*)  d_in[1];
    const float* ew = (const float*)d_in[2];
    const float* W1 = (const float*)d_in[3];
    const float* b1 = (const float*)d_in[4];
    const float* W2 = (const float*)d_in[5];
    const float* b2 = (const float*)d_in[6];

    const int N = in_sizes[0];       // x is [N,1], N=100000 -> NB=25 buckets
    const int E = in_sizes[2];       // edge_attr is [E]
    const int* row = ei;             // edge_index[0] = source
    const int* col = ei + E;         // edge_index[1] = target
    const int eb  = (E + EPB - 1) / EPB;         // 611
    const int ebp = (eb + 63) & ~63;             // 640

    // workspace layout (~64 MB), 256 B aligned
    char* wsp = (char*)d_ws;
    auto take = [&](size_t bytes) {
        char* r = wsp; wsp += (bytes + 255) & ~(size_t)255; return (void*)r;
    };
    i2*    rec  = (i2*)   take((size_t)NT2 * TCAP * 8);     // 49.3 MB
    float* part = (float*)take((size_t)NT2 * BS * 4);       // 10.2 MB
    float* dinv = (float*)take((size_t)N * 4);
    float* p    = (float*)take((size_t)N * 4);
    float* q    = (float*)take((size_t)N * 4);
    int*   cntT = (int*)  take((size_t)NT2 * ebp * 4);      // 1.6 MB
    int*   ofsT = (int*)  take((size_t)NT2 * ebp * 4);      // 1.6 MB
    int*   tot  = (int*)  take((size_t)NT2 * 4);

    float* out = (float*)d_out;

    const int nbk = (N + T - 1) / T;             // 391

    k_count  <<<eb,  T, 0, stream>>>(row, col, cntT, E, ebp);
    k_scan   <<<NT2, T, 0, stream>>>(cntT, ofsT, tot, eb, ebp);
    k_scatter<<<eb,  T, 0, stream>>>(row, col, ew, ofsT, rec, E, ebp);

    // degree
    k_acc2<false><<<NT2, T, 0, stream>>>(rec, tot, nullptr, part, N);
    k_dinv       <<<nbk, T, 0, stream>>>(part, x, dinv, p, N);

    // layer 1
    k_acc2<true><<<NT2, T, 0, stream>>>(rec, tot, p, part, N);
    k_mlp       <<<nbk, T, 0, stream>>>(part, dinv, p, W1, b1, W2, q, N);

    // layer 2
    k_acc2<true><<<NT2, T, 0, stream>>>(rec, tot, q, part, N);
    k_out       <<<nbk, T, 0, stream>>>(part, dinv, q, b2, out, N);
}

// Round 10
// 268.908 us; speedup vs baseline: 3.2785x; 1.2059x over previous
//
#include <hip/hip_runtime.h>

#define T       256
#define BSHIFT  12
#define BSIZE   4096            // nodes per bucket
#define MAXNB   32              // max buckets (N<=131072)
#define M       64              // accumulate slices per bucket
#define EPB     2048            // edges per count/scatter block (18 KB LDS -> 8 blocks/CU)
#define EPT     (EPB / T)       // 8 edges per thread

typedef int   i4 __attribute__((ext_vector_type(4)));
typedef int   i2v __attribute__((ext_vector_type(2)));
typedef float f4 __attribute__((ext_vector_type(4)));

// ---------- count: per-block bucket histogram -> transposed count matrix ----------
__global__ __launch_bounds__(T) void k_count(const int* __restrict__ col,
                                             int* __restrict__ cntT,
                                             int E, int nb, int ebp) {
    __shared__ int hist[MAXNB];
    int t = threadIdx.x, g = blockIdx.x;
    if (t < MAXNB) hist[t] = 0;
    __syncthreads();
    int base = g * EPB;
    bool full = (base + EPB <= E);
    if (full) {
#pragma unroll
        for (int k = 0; k < EPT / 4; ++k) {
            i4 c = __builtin_nontemporal_load((const i4*)(col + base + (t + k * T) * 4));
            atomicAdd(&hist[c.x >> BSHIFT], 1);
            atomicAdd(&hist[c.y >> BSHIFT], 1);
            atomicAdd(&hist[c.z >> BSHIFT], 1);
            atomicAdd(&hist[c.w >> BSHIFT], 1);
        }
    } else {
        for (int k = 0; k < EPT; ++k) {
            int e = base + t + k * T;
            if (e < E) atomicAdd(&hist[col[e] >> BSHIFT], 1);
        }
    }
    __syncthreads();
    if (t < nb) cntT[t * ebp + g] = hist[t];
}

// ---------- scan: one block per bucket, shfl-based exclusive scan ----------
__global__ __launch_bounds__(T) void k_scan(const int* __restrict__ cntT,
                                            int* __restrict__ ofsT,
                                            int* __restrict__ tot, int eb, int ebp) {
    __shared__ int wsum[4];
    __shared__ int carry;
    int b = blockIdx.x, t = threadIdx.x, lane = t & 63, wid = t >> 6;
    if (t == 0) carry = 0;
    __syncthreads();
    int rounds = (eb + T - 1) / T;
    for (int jr = 0; jr < rounds; ++jr) {
        int idx = jr * T + t;
        int v = (idx < eb) ? cntT[b * ebp + idx] : 0;
        int inc = v;
#pragma unroll
        for (int d = 1; d < 64; d <<= 1) {
            int o = __shfl_up(inc, d, 64);
            if (lane >= d) inc += o;
        }
        if (lane == 63) wsum[wid] = inc;
        __syncthreads();
        int add = carry;
        for (int w = 0; w < wid; ++w) add += wsum[w];
        if (idx < eb) ofsT[b * ebp + idx] = inc - v + add;
        __syncthreads();
        if (t == 0) carry += wsum[0] + wsum[1] + wsum[2] + wsum[3];
        __syncthreads();
    }
    if (t == 0) tot[b] = carry;
}

// ---------- scatter: LDS bucket-sort one 2048-edge tile, coalesced copy-out ----------
// record.x = (col & 4095) << 17 | row  (row < 2^17), record.y = bits(w)
__global__ __launch_bounds__(T) void k_scatter(
        const int* __restrict__ row, const int* __restrict__ col,
        const float* __restrict__ w,
        const int* __restrict__ cntT, const int* __restrict__ ofsT,
        const int* __restrict__ tot,
        i2v* __restrict__ rec, int E, int nb, int ebp) {
    __shared__ int  lofs[MAXNB + 1];
    __shared__ int  rnk[MAXNB];
    __shared__ int  rbase[MAXNB];
    __shared__ i2v  buf[EPB];          // 16 KB
    __shared__ unsigned char bkt[EPB]; // 2 KB
    int t = threadIdx.x, g = blockIdx.x;
    if (t < MAXNB) rnk[t] = 0;
    if (t < 64) {
        // scan padded tot (x4) -> bucket bases (exclusive), in-lane
        int tv = (t < nb) ? ((tot[t] + 3) & ~3) : 0;
        int incA = tv;
#pragma unroll
        for (int d = 1; d < 32; d <<= 1) {
            int o = __shfl_up(incA, d, 64);
            if (t >= d) incA += o;
        }
        // scan this block's count row -> tile-local offsets
        int h = (t < nb) ? cntT[t * ebp + g] : 0;
        int incB = h;
#pragma unroll
        for (int d = 1; d < 32; d <<= 1) {
            int o = __shfl_up(incB, d, 64);
            if (t >= d) incB += o;
        }
        if (t == 0) lofs[0] = 0;
        if (t < nb) {
            lofs[t + 1] = incB;
            rbase[t] = (incA - tv) + ofsT[t * ebp + g];   // bucket base + my offset
        }
    }
    __syncthreads();

    int base = g * EPB;
    bool full = (base + EPB <= E);
    if (full) {
#pragma unroll
        for (int k = 0; k < EPT / 4; ++k) {
            int idx = base + (t + k * T) * 4;
            i4 c  = __builtin_nontemporal_load((const i4*)(col + idx));
            i4 r  = __builtin_nontemporal_load((const i4*)(row + idx));
            f4 wv = __builtin_nontemporal_load((const f4*)(w + idx));
            int b, rk, pos;
            i2v v;
            b = c.x >> BSHIFT; rk = atomicAdd(&rnk[b], 1); pos = lofs[b] + rk;
            v.x = ((c.x & (BSIZE-1)) << 17) | r.x; v.y = __float_as_int(wv.x);
            buf[pos] = v; bkt[pos] = (unsigned char)b;
            b = c.y >> BSHIFT; rk = atomicAdd(&rnk[b], 1); pos = lofs[b] + rk;
            v.x = ((c.y & (BSIZE-1)) << 17) | r.y; v.y = __float_as_int(wv.y);
            buf[pos] = v; bkt[pos] = (unsigned char)b;
            b = c.z >> BSHIFT; rk = atomicAdd(&rnk[b], 1); pos = lofs[b] + rk;
            v.x = ((c.z & (BSIZE-1)) << 17) | r.z; v.y = __float_as_int(wv.z);
            buf[pos] = v; bkt[pos] = (unsigned char)b;
            b = c.w >> BSHIFT; rk = atomicAdd(&rnk[b], 1); pos = lofs[b] + rk;
            v.x = ((c.w & (BSIZE-1)) << 17) | r.w; v.y = __float_as_int(wv.w);
            buf[pos] = v; bkt[pos] = (unsigned char)b;
        }
    } else {
        for (int k = 0; k < EPT; ++k) {
            int e = base + t + k * T;
            if (e < E) {
                int c = col[e];
                int b = c >> BSHIFT;
                int rk = atomicAdd(&rnk[b], 1);
                int pos = lofs[b] + rk;
                i2v v;
                v.x = ((c & (BSIZE-1)) << 17) | row[e];
                v.y = __float_as_int(w[e]);
                buf[pos] = v; bkt[pos] = (unsigned char)b;
            }
        }
    }
    __syncthreads();
    int total = lofs[nb];
    for (int j = t; j < total; j += T) {       // coalesced copy-out
        int b = bkt[j];
        __builtin_nontemporal_store(buf[j], &rec[rbase[b] + (j - lofs[b])]);
    }
}

// ---------- accumulate: LDS scatter-add of one bucket slice ----------
template <bool HAS_SRC>
__global__ __launch_bounds__(T) void k_acc(
        const i2v* __restrict__ rec, const int* __restrict__ tot,
        const float* __restrict__ src, float* __restrict__ part, int nb) {
    __shared__ float acc[BSIZE];
    __shared__ int   bst[MAXNB];
    int t = threadIdx.x, g = blockIdx.x;
    int b = g / M, m = g % M;
    if (t < 64) {                               // bucket bases from padded tot
        int tv = (t < nb) ? ((tot[t] + 3) & ~3) : 0;
        int inc = tv;
#pragma unroll
        for (int d = 1; d < 32; d <<= 1) {
            int o = __shfl_up(inc, d, 64);
            if (t >= d) inc += o;
        }
        if (t < nb) bst[t] = inc - tv;
    }
    f4* acc4 = (f4*)acc;
    for (int j = t; j < BSIZE / 4; j += T) acc4[j] = (f4){0.f, 0.f, 0.f, 0.f};
    __syncthreads();
    int s  = bst[b];
    int tb = tot[b];
    int chunk = ((tb + M - 1) / M + 7) & ~7;    // x8 records per slice
    int lo = s + m * chunk;
    int hi = min(s + tb, lo + chunk);
    const i4* rec4 = (const i4*)rec;
    int i = lo + t * 8;
    for (; i + 7 < hi; i += T * 8) {
        i4 q0 = __builtin_nontemporal_load(rec4 + (i >> 1) + 0);
        i4 q1 = __builtin_nontemporal_load(rec4 + (i >> 1) + 1);
        i4 q2 = __builtin_nontemporal_load(rec4 + (i >> 1) + 2);
        i4 q3 = __builtin_nontemporal_load(rec4 + (i >> 1) + 3);
        float v0 = __int_as_float(q0.y), v1 = __int_as_float(q0.w);
        float v2 = __int_as_float(q1.y), v3 = __int_as_float(q1.w);
        float v4 = __int_as_float(q2.y), v5 = __int_as_float(q2.w);
        float v6 = __int_as_float(q3.y), v7 = __int_as_float(q3.w);
        if (HAS_SRC) {
            v0 *= src[q0.x & 0x1FFFF]; v1 *= src[q0.z & 0x1FFFF];
            v2 *= src[q1.x & 0x1FFFF]; v3 *= src[q1.z & 0x1FFFF];
            v4 *= src[q2.x & 0x1FFFF]; v5 *= src[q2.z & 0x1FFFF];
            v6 *= src[q3.x & 0x1FFFF]; v7 *= src[q3.z & 0x1FFFF];
        }
        atomicAdd(&acc[((unsigned)q0.x) >> 17], v0);
        atomicAdd(&acc[((unsigned)q0.z) >> 17], v1);
        atomicAdd(&acc[((unsigned)q1.x) >> 17], v2);
        atomicAdd(&acc[((unsigned)q1.z) >> 17], v3);
        atomicAdd(&acc[((unsigned)q2.x) >> 17], v4);
        atomicAdd(&acc[((unsigned)q2.z) >> 17], v5);
        atomicAdd(&acc[((unsigned)q3.x) >> 17], v6);
        atomicAdd(&acc[((unsigned)q3.z) >> 17], v7);
    }
    for (; i < hi; ++i) {                       // tail owned by exactly one thread
        i2v r = rec[i];
        float v = __int_as_float(r.y);
        if (HAS_SRC) v *= src[r.x & 0x1FFFF];
        atomicAdd(&acc[((unsigned)r.x) >> 17], v);
    }
    __syncthreads();
    f4* dst4 = (f4*)(part + (size_t)g * BSIZE);
    for (int j = t; j < BSIZE / 4; j += T)
        __builtin_nontemporal_store(acc4[j], dst4 + j);
}

// ---------- reduce + pointwise ----------
__device__ __forceinline__ float reduceM(const float* __restrict__ part, int n) {
    int b = n >> BSHIFT, o = n & (BSIZE - 1);
    const float* pp = part + (size_t)b * M * BSIZE + o;
    float s = 0.0f;
#pragma unroll
    for (int m = 0; m < M; ++m)
        s += __builtin_nontemporal_load(pp + (size_t)m * BSIZE);
    return s;
}

__global__ void k_red_dinv(const float* __restrict__ part, const float* __restrict__ x,
                           float* __restrict__ dinv, float* __restrict__ p, int N) {
    int i = blockIdx.x * blockDim.x + threadIdx.x;
    if (i < N) {
        float d  = reduceM(part, i) + 1.0f;     // +1 = self-loop
        float di = rsqrtf(d);
        dinv[i] = di;
        p[i] = di * x[i];
    }
}

__global__ void k_red_mlp(const float* __restrict__ part, const float* __restrict__ dinv,
                          const float* __restrict__ p,
                          const float* __restrict__ W1, const float* __restrict__ b1,
                          const float* __restrict__ W2,
                          float* __restrict__ q, int N) {
    int i = blockIdx.x * blockDim.x + threadIdx.x;
    if (i < N) {
        float di = dinv[i];
        float s  = di * reduceM(part, i) + di * p[i];
        float acc = 0.0f;
#pragma unroll
        for (int k = 0; k < 16; ++k) {
            float h = fmaxf(s * W1[k] + b1[k], 0.0f);
            acc += h * W2[k];
        }
        q[i] = di * acc;
    }
}

__global__ void k_red_out(const float* __restrict__ part, const float* __restrict__ dinv,
                          const float* __restrict__ q, const float* __restrict__ b2,
                          float* __restrict__ out, int N) {
    int i = blockIdx.x * blockDim.x + threadIdx.x;
    if (i < N) {
        float di = dinv[i];
        out[i] = di * reduceM(part, i) + di * q[i] + b2[0];
    }
}

extern "C" void kernel_launch(void* const* d_in, const int* in_sizes, int n_in,
                              void* d_out, int out_size, void* d_ws, size_t ws_size,
                              hipStream_t stream) {
    const float* x  = (const float*)d_in[0];
    const int*   ei = (const int*)  d_in[1];
    const float* ew = (const float*)d_in[2];
    const float* W1 = (const float*)d_in[3];
    const float* b1 = (const float*)d_in[4];
    const float* W2 = (const float*)d_in[5];
    const float* b2 = (const float*)d_in[6];

    const int N = in_sizes[0];       // x is [N,1]
    const int E = in_sizes[2];       // edge_attr is [E]
    const int* row = ei;             // edge_index[0] = source
    const int* col = ei + E;         // edge_index[1] = target
    const int nb  = (N + BSIZE - 1) >> BSHIFT;   // 25
    const int eb  = (E + EPB - 1) / EPB;         // 2442
    const int ebp = (eb + 63) & ~63;             // padded row length

    // workspace layout (~68 MB), 256 B aligned
    char* wsp = (char*)d_ws;
    auto take = [&](size_t bytes) {
        char* r = wsp; wsp += (bytes + 255) & ~(size_t)255; return (void*)r;
    };
    i2v*   rec  = (i2v*)  take((size_t)(E + 4 * MAXNB) * 8);   // 40.07 MB
    float* part = (float*)take((size_t)nb * M * BSIZE * 4);    // 26.2 MB
    float* dinv = (float*)take((size_t)N * 4);
    float* p    = (float*)take((size_t)N * 4);
    float* q    = (float*)take((size_t)N * 4);
    int*   cntT = (int*)  take((size_t)MAXNB * ebp * 4);       // 0.32 MB
    int*   ofsT = (int*)  take((size_t)MAXNB * ebp * 4);       // 0.32 MB
    int*   tot  = (int*)  take(MAXNB * 4);

    float* out = (float*)d_out;

    const int nbk = (N + T - 1) / T;
    const int ab  = nb * M;                      // 1600

    k_count  <<<eb, T, 0, stream>>>(col, cntT, E, nb, ebp);
    k_scan   <<<nb, T, 0, stream>>>(cntT, ofsT, tot, eb, ebp);
    k_scatter<<<eb, T, 0, stream>>>(row, col, ew, cntT, ofsT, tot, rec, E, nb, ebp);

    // degree
    k_acc<false><<<ab, T, 0, stream>>>(rec, tot, nullptr, part, nb);
    k_red_dinv  <<<nbk, T, 0, stream>>>(part, x, dinv, p, N);

    // layer 1
    k_acc<true><<<ab, T, 0, stream>>>(rec, tot, p, part, nb);
    k_red_mlp  <<<nbk, T, 0, stream>>>(part, dinv, p, W1, b1, W2, q, N);

    // layer 2
    k_acc<true><<<ab, T, 0, stream>>>(rec, tot, q, part, nb);
    k_red_out  <<<nbk, T, 0, stream>>>(part, dinv, q, b2, out, N);
}